// Round 12
// baseline (174.178 us; speedup 1.0000x reference)
//
#include <hip/hip_runtime.h>
#include <cstdint>
#include <cstddef>

#define B_   2
#define N_   2048
#define D_   1024
#define H_   16
#define HD_  64
// SCALE * log2(e), folded into Q in the GEMM epilogue
#define QSCALE_ 0.18033688011112042f

typedef unsigned short u16;
typedef unsigned int   u32;
typedef __attribute__((ext_vector_type(8))) short short8;   // bf16 MFMA A/B frag
typedef __attribute__((ext_vector_type(4))) float f32x4;    // MFMA C/D frag (16x16)
typedef __attribute__((ext_vector_type(16))) float f32x16;  // MFMA C/D frag (32x32)
typedef __attribute__((ext_vector_type(4))) float fl4;
typedef __attribute__((ext_vector_type(4))) unsigned short us4;
typedef __attribute__((ext_vector_type(4))) unsigned int u32x4;

#if __has_builtin(__builtin_amdgcn_exp2f)
#define EXP2F(x) __builtin_amdgcn_exp2f(x)   // raw v_exp_f32, no OCML denorm guards
#else
#define EXP2F(x) exp2f(x)
#endif

__device__ __forceinline__ u16 f2bf(float f) {
  u32 u = __builtin_bit_cast(u32, f);
  u += 0x7fffu + ((u >> 16) & 1u);   // RNE; inputs finite
  return (u16)(u >> 16);
}

// pack two f32 -> one u32 of 2 bf16 (RNE), elem0 in low half
__device__ __forceinline__ u32 cvtpk(float lo, float hi) {
  u32 r;
  asm("v_cvt_pk_bf16_f32 %0, %1, %2" : "=v"(r) : "v"(lo), "v"(hi));
  return r;
}

// v_permlane32_swap_b32 a, b: a[32:63] <-> b[0:31]
__device__ __forceinline__ void plswap(u32& a, u32& b) {
  asm volatile("v_permlane32_swap_b32 %0, %1" : "+v"(a), "+v"(b));
}

__device__ __forceinline__ void gload16(const void* g, void* l) {
  typedef __attribute__((address_space(1))) unsigned int gu32;
  typedef __attribute__((address_space(3))) unsigned int lu32;
  __builtin_amdgcn_global_load_lds((gu32*)g, (lu32*)l, 16, 0, 0);
}

// ---------------- fp32 -> bf16 conversion of x1, x2, W ----------------
// Convert-once matters beyond FLOPs: bf16 panels keep the qkv staging working
// set L2-resident (R4 evidence: f32 direct reads -> FETCH 69->191MB, 1.75x slower).
__global__ void convert_kernel(const fl4* __restrict__ x1, const fl4* __restrict__ x2,
                               const fl4* __restrict__ w,
                               us4* __restrict__ o1, us4* __restrict__ o2,
                               us4* __restrict__ ow) {
  const int NX = (B_ * N_ * D_) / 4;   // 1048576
  const int NW = (3 * D_ * D_) / 4;    // 786432
  int stride = gridDim.x * blockDim.x;
  for (int i = blockIdx.x * blockDim.x + threadIdx.x; i < NX; i += stride) {
    fl4 a = x1[i];
    us4 r; r.x = f2bf(a.x); r.y = f2bf(a.y); r.z = f2bf(a.z); r.w = f2bf(a.w);
    o1[i] = r;
    fl4 b = x2[i];
    us4 s; s.x = f2bf(b.x); s.y = f2bf(b.y); s.z = f2bf(b.z); s.w = f2bf(b.w);
    o2[i] = s;
    if (i < NW) {
      fl4 c = w[i];
      us4 t; t.x = f2bf(c.x); t.y = f2bf(c.y); t.z = f2bf(c.z); t.w = f2bf(c.w);
      ow[i] = t;
    }
  }
}

// ---------------- fused QKV GEMM v6 (CHAMPION, R8/R11: ~46us): 2-barrier + BK=64 + swizzle ----
// Ledger: 48.9 (2-bar BK32) / 49.7 (1-bar dbuf) / 61.9 (vmcnt ring) / 56.9 (z-XCD) /
// 47.0 (THIS) / 64.8 (256² 1-drain, 1 blk/CU) / 101.9 (128x64 6-blk, HBM-bound).
// Every structural departure regressed — this is the measured optimum of the family.
// Swizzle (measured 0 conflicts): LINEAR gload_lds dest + inverse-swizzled global SOURCE
// (granule (l&7)^(l>>3), same 128B segment -> coalescing kept) + swizzled READ offsets
// ((quad^(col&7))*8, k-high frag at ^32).
// z=0: Q from x1 -> [B,H,N,HD] (pre-scaled by SCALE*log2e); z=1: K from x2; z=2: V -> Vt.
__global__ __launch_bounds__(256) void qkv_gemm(
    const u16* __restrict__ x1b, const u16* __restrict__ x2b,
    const u16* __restrict__ wb, const float* __restrict__ bias,
    u16* __restrict__ Qb, u16* __restrict__ Kb, u16* __restrict__ Vtb) {
  const int z = blockIdx.z;
  const u16* X = (z == 0) ? x1b : x2b;
  const u16* W = wb + (size_t)z * D_ * D_;
  const float* bz = bias + z * D_;
  const int m0 = blockIdx.y * 128;
  const int e0 = blockIdx.x * 128;
  const int tid = threadIdx.x;
  const int lane = tid & 63;
  const int w = tid >> 6;
  const int wr = w >> 1, wc = w & 1;
  const int col = lane & 15, quad = lane >> 4;

  __shared__ __align__(16) u16 As[128 * 64];   // [row][64], granule-swizzled
  __shared__ __align__(16) u16 Bs[128 * 64];

  f32x4 acc[4][4] = {};

  const int cg = (lane & 7) ^ (lane >> 3);
  const u16* sA = X + (size_t)(m0 + w * 8 + (lane >> 3)) * D_ + cg * 8;
  const u16* sB = W + (size_t)(e0 + w * 8 + (lane >> 3)) * D_ + cg * 8;
  u16* dA = &As[w * 512];                      // wave-uniform; HW adds lane*16B
  u16* dB = &Bs[w * 512];

  const int pg = (quad ^ (col & 7)) * 8;       // frag k=0..31; frag k=32..63 at pg^32

  for (int k0 = 0; k0 < D_; k0 += 64) {
    __syncthreads();                           // write-after-read: all waves done with tile
#pragma unroll
    for (int rr = 0; rr < 4; ++rr) {
      gload16(sA + (size_t)rr * 32 * D_ + k0, dA + rr * 2048);
      gload16(sB + (size_t)rr * 32 * D_ + k0, dB + rr * 2048);
    }
    __syncthreads();                           // drain: tile resident

    short8 a[4][2], b[4][2];
#pragma unroll
    for (int i = 0; i < 4; ++i) {
      const int rb = (wr * 64 + i * 16 + col) * 64;
      a[i][0] = *(const short8*)&As[rb + pg];
      a[i][1] = *(const short8*)&As[rb + (pg ^ 32)];
    }
#pragma unroll
    for (int j = 0; j < 4; ++j) {
      const int rb = (wc * 64 + j * 16 + col) * 64;
      b[j][0] = *(const short8*)&Bs[rb + pg];
      b[j][1] = *(const short8*)&Bs[rb + (pg ^ 32)];
    }
    __builtin_amdgcn_s_setprio(1);
#pragma unroll
    for (int i = 0; i < 4; ++i)
#pragma unroll
      for (int j = 0; j < 4; ++j) {
        acc[i][j] = __builtin_amdgcn_mfma_f32_16x16x32_bf16(a[i][0], b[j][0], acc[i][j], 0, 0, 0);
        acc[i][j] = __builtin_amdgcn_mfma_f32_16x16x32_bf16(a[i][1], b[j][1], acc[i][j], 0, 0, 0);
      }
    __builtin_amdgcn_s_setprio(0);
  }

#pragma unroll
  for (int j = 0; j < 4; ++j) {
    int eg = e0 + wc * 64 + j * 16 + col;
    float bj = bz[eg];
    int h = eg >> 6, d = eg & 63;
#pragma unroll
    for (int i = 0; i < 4; ++i) {
#pragma unroll
      for (int r = 0; r < 4; ++r) {
        int m = m0 + wr * 64 + i * 16 + quad * 4 + r;
        int bb = m >> 11, n = m & (N_ - 1);
        float v = acc[i][j][r] + bj;
        if (z == 0) v *= QSCALE_;
        u16 o = f2bf(v);
        if (z == 0)      Qb [(((size_t)bb * H_ + h) * N_ + n) * HD_ + d] = o;
        else if (z == 1) Kb [(((size_t)bb * H_ + h) * N_ + n) * HD_ + d] = o;
        else             Vtb[(((size_t)bb * H_ + h) * HD_ + d) * N_ + n] = o;
      }
    }
  }
}

// ---------------- fused attention v6: champion v5 + 2-deep register prefetch ----------------
// R11 counters: attn 45.8us, MfmaUtil 29 / VALU 39 / HBM 19 — latency-bound; ~1/3 of K/V
// prefetches miss to HBM (~900cy) but the 1-deep schedule gives only ~1 tile (~500cy) of
// issue->consume cover (loads issued after the barrier, committed at the SAME iteration's
// tail).  v6: register double-buffer (set0/set1, +16 VGPR), loop unrolled x2 (static reg
// indexing, rule #20): body(t) issues loads for tile t+2 and commits tile t+1's regs
// (loaded one full iteration earlier) -> ~2 tiles (~1000cy) of cover.  Barrier structure,
// LDS layout, compute, epilogue byte-identical to the champion; same write-after-read
// invariant (buf written at tail of body(t) was last read in body(t-1), barrier between).
__global__ __launch_bounds__(256, 2) void attn_kernel(
    const u16* __restrict__ Qb, const u16* __restrict__ Kb,
    const u16* __restrict__ Vtb, float* __restrict__ out) {
  const int bh = blockIdx.y;                 // 0..31
  const int bb = bh >> 4, h = bh & 15;
  const int q0 = blockIdx.x * 128;
  const int tid = threadIdx.x;
  const int lane = tid & 63;
  const int w = tid >> 6;
  const int l31 = lane & 31, hf = lane >> 5, r7 = lane & 7;

  const u16* __restrict__ Q  = Qb  + ((size_t)bh << 17);   // bh * N*HD
  const u16* __restrict__ K  = Kb  + ((size_t)bh << 17);
  const u16* __restrict__ Vt = Vtb + ((size_t)bh << 17);

  __shared__ __align__(16) u16 Ks[2][64 * 64];   // [buf][key][d]  swizzled
  __shared__ __align__(16) u16 Vs[2][64 * 64];   // [buf][d][key]  swizzled
  __shared__ float Ls[4][32];                    // per-wave 1/denominator

  // Q B-frags: col = q = l31, chunk c covers d = c*16 + hf*8 + j
  const u16* Qr = Q + (size_t)(q0 + w * 32 + l31) * HD_;
  short8 qf[4];
#pragma unroll
  for (int c = 0; c < 4; ++c)
    qf[c] = *(const short8*)&Qr[c * 16 + hf * 8];

  // cooperative staging: 256 threads x 16B granules; swizzled write slots
  const int srow = tid >> 3;              // 0..31
  const int sg   = tid & 7;
  const int lw0 = srow * 64 + ((sg ^ (srow & 7)) * 8);
  const int lw1 = lw0 + 2048;                            // row+32: (row&7) unchanged
  const u16* gK = K + tid * 8;                           // + k0*64 (+2048 rows 32..63)
  const u16* gV = Vt + srow * N_ + sg * 8;               // + k0   (+32*N_ d 32..63)

  f32x16 accO[2] = {};
  float lsum = 0.f;

  // per-tile compute: S^T = mfma(K,Q) -> exp2 -> in-reg cvtpk/permlane -> PV
#define ATT_TILE(CUR)                                                          \
  do {                                                                         \
    const u16* Kc = Ks[CUR];                                                   \
    const u16* Vc = Vs[CUR];                                                   \
    f32x16 sT[2] = {};                                                         \
    __builtin_amdgcn_s_setprio(1);                                             \
    _Pragma("unroll")                                                          \
    for (int kb = 0; kb < 2; ++kb) {                                           \
      const int rb = (kb * 32 + l31) * 64;                                     \
      _Pragma("unroll")                                                        \
      for (int c = 0; c < 4; ++c) {                                            \
        short8 kf = *(const short8*)&Kc[rb + (((c * 2 + hf) ^ r7) * 8)];       \
        sT[kb] = __builtin_amdgcn_mfma_f32_32x32x16_bf16(kf, qf[c], sT[kb],    \
                                                         0, 0, 0);             \
      }                                                                        \
    }                                                                          \
    __builtin_amdgcn_s_setprio(0);                                             \
    _Pragma("unroll")                                                          \
    for (int kb = 0; kb < 2; ++kb)                                             \
      _Pragma("unroll")                                                        \
      for (int i = 0; i < 16; ++i) {                                           \
        float e = EXP2F(sT[kb][i]);                                            \
        lsum += e;                                                             \
        sT[kb][i] = e;                                                         \
      }                                                                        \
    short8 pf[4];                                                              \
    _Pragma("unroll")                                                          \
    for (int kc = 0; kc < 4; ++kc) {                                           \
      const int kb = kc >> 1, o = (kc & 1) * 8;                                \
      u32 Xp = cvtpk(sT[kb][o + 0], sT[kb][o + 1]);                            \
      u32 Yp = cvtpk(sT[kb][o + 4], sT[kb][o + 5]);                            \
      plswap(Xp, Yp);                                                          \
      u32 Zp = cvtpk(sT[kb][o + 2], sT[kb][o + 3]);                            \
      u32 Wp = cvtpk(sT[kb][o + 6], sT[kb][o + 7]);                            \
      plswap(Zp, Wp);                                                          \
      u32x4 pw = {Xp, Zp, Yp, Wp};                                             \
      pf[kc] = __builtin_bit_cast(short8, pw);                                 \
    }                                                                          \
    __builtin_amdgcn_s_setprio(1);                                             \
    _Pragma("unroll")                                                          \
    for (int db = 0; db < 2; ++db) {                                           \
      const int rb = (db * 32 + l31) * 64;                                     \
      _Pragma("unroll")                                                        \
      for (int kc = 0; kc < 4; ++kc) {                                         \
        short8 vf = *(const short8*)&Vc[rb + (((kc * 2 + hf) ^ r7) * 8)];      \
        accO[db] = __builtin_amdgcn_mfma_f32_32x32x16_bf16(pf[kc], vf,         \
                                                           accO[db], 0, 0, 0);\
      }                                                                        \
    }                                                                          \
    __builtin_amdgcn_s_setprio(0);                                             \
  } while (0)

  // prologue: tile 0 -> regs -> buf 0; tile 1 -> set0 (in flight)
  short8 kA0 = *(const short8*)(gK);
  short8 kB0 = *(const short8*)(gK + 2048);
  short8 vA0 = *(const short8*)(gV);
  short8 vB0 = *(const short8*)(gV + 32 * N_);
  *(short8*)&Ks[0][lw0] = kA0;
  *(short8*)&Ks[0][lw1] = kB0;
  *(short8*)&Vs[0][lw0] = vA0;
  *(short8*)&Vs[0][lw1] = vB0;
  kA0 = *(const short8*)(gK + 64 * 64);
  kB0 = *(const short8*)(gK + 64 * 64 + 2048);
  vA0 = *(const short8*)(gV + 64);
  vB0 = *(const short8*)(gV + 64 + 32 * N_);
  short8 kA1, kB1, vA1, vB1;

  const int NT = N_ / 64;                     // 32, even
  for (int tt = 0; tt < NT; tt += 2) {
    // ---- body t = tt (even): compute buf0; issue t+2 -> set1; commit set0(t+1) -> buf1
    __syncthreads();                          // buf0 committed & visible
    if (tt + 2 < NT) {
      const int k0n = (tt + 2) * 64;
      kA1 = *(const short8*)(gK + k0n * 64);
      kB1 = *(const short8*)(gK + k0n * 64 + 2048);
      vA1 = *(const short8*)(gV + k0n);
      vB1 = *(const short8*)(gV + k0n + 32 * N_);
    }
    ATT_TILE(0);
    // tile tt+1 always exists (tt <= NT-2); loads issued one full iteration ago
    *(short8*)&Ks[1][lw0] = kA0;
    *(short8*)&Ks[1][lw1] = kB0;
    *(short8*)&Vs[1][lw0] = vA0;
    *(short8*)&Vs[1][lw1] = vB0;

    // ---- body t = tt+1 (odd): compute buf1; issue t+3 -> set0; commit set1(t+2) -> buf0
    __syncthreads();                          // buf1 committed & visible
    if (tt + 3 < NT) {
      const int k0n = (tt + 3) * 64;
      kA0 = *(const short8*)(gK + k0n * 64);
      kB0 = *(const short8*)(gK + k0n * 64 + 2048);
      vA0 = *(const short8*)(gV + k0n);
      vB0 = *(const short8*)(gV + k0n + 32 * N_);
    }
    ATT_TILE(1);
    if (tt + 2 < NT) {
      *(short8*)&Ks[0][lw0] = kA1;
      *(short8*)&Ks[0][lw1] = kB1;
      *(short8*)&Vs[0][lw0] = vA1;
      *(short8*)&Vs[0][lw1] = vB1;
    }
  }
#undef ATT_TILE

  // denominator: lane pair (l, l^32) holds complementary key halves for q = l31
  lsum += __shfl_xor(lsum, 32);
  if (hf == 0) Ls[w][l31] = 1.0f / lsum;
  __syncthreads();

  float rinv[16];
#pragma unroll
  for (int r = 0; r < 16; ++r)
    rinv[r] = Ls[w][(r & 3) + 8 * (r >> 2) + 4 * hf];

#pragma unroll
  for (int db = 0; db < 2; ++db)
#pragma unroll
    for (int r = 0; r < 16; ++r) {
      int n = q0 + w * 32 + (r & 3) + 8 * (r >> 2) + 4 * hf;
      int e = h * HD_ + db * 32 + l31;
      out[((size_t)bb * N_ + n) * D_ + e] = accO[db][r] * rinv[r];
    }
}

extern "C" void kernel_launch(void* const* d_in, const int* in_sizes, int n_in,
                              void* d_out, int out_size, void* d_ws, size_t ws_size,
                              hipStream_t stream) {
  const float* x1 = (const float*)d_in[0];
  const float* x2 = (const float*)d_in[1];
  const float* qw = (const float*)d_in[2];
  const float* qb = (const float*)d_in[3];
  float* out = (float*)d_out;

  u16* ws   = (u16*)d_ws;
  u16* x1b  = ws;                       // 4194304
  u16* x2b  = ws + 4194304;             // 4194304
  u16* wb   = ws + 8388608;             // 3145728
  u16* Qbf  = ws + 11534336;            // 4194304  [B,H,N,HD] (pre-scaled)
  u16* Kbf  = ws + 15728640;            // 4194304  [B,H,N,HD]
  u16* Vtb  = ws + 19922944;            // 4194304  [B,H,HD,N]
  if (ws_size < (size_t)24117248 * 2) return;

  convert_kernel<<<dim3(1024), dim3(256), 0, stream>>>(
      (const fl4*)x1, (const fl4*)x2, (const fl4*)qw,
      (us4*)x1b, (us4*)x2b, (us4*)wb);

  qkv_gemm<<<dim3(8, 32, 3), dim3(256), 0, stream>>>(
      x1b, x2b, wb, qb, Qbf, Kbf, Vtb);

  attn_kernel<<<dim3(16, 32), dim3(256), 0, stream>>>(Qbf, Kbf, Vtb, out);
}

// Round 13
// 164.789 us; speedup vs baseline: 1.0570x; 1.0570x over previous
//
#include <hip/hip_runtime.h>
#include <cstdint>
#include <cstddef>

#define B_   2
#define N_   2048
#define D_   1024
#define H_   16
#define HD_  64
// SCALE * log2(e), folded into Q in the GEMM epilogue
#define QSCALE_ 0.18033688011112042f

typedef unsigned short u16;
typedef unsigned int   u32;
typedef __attribute__((ext_vector_type(8))) short short8;   // bf16 MFMA A/B frag
typedef __attribute__((ext_vector_type(4))) float f32x4;    // MFMA C/D frag (16x16)
typedef __attribute__((ext_vector_type(16))) float f32x16;  // MFMA C/D frag (32x32)
typedef __attribute__((ext_vector_type(4))) float fl4;
typedef __attribute__((ext_vector_type(4))) unsigned short us4;
typedef __attribute__((ext_vector_type(4))) unsigned int u32x4;

#if __has_builtin(__builtin_amdgcn_exp2f)
#define EXP2F(x) __builtin_amdgcn_exp2f(x)   // raw v_exp_f32, no OCML denorm guards
#else
#define EXP2F(x) exp2f(x)
#endif

__device__ __forceinline__ u16 f2bf(float f) {
  u32 u = __builtin_bit_cast(u32, f);
  u += 0x7fffu + ((u >> 16) & 1u);   // RNE; inputs finite
  return (u16)(u >> 16);
}

// pack two f32 -> one u32 of 2 bf16 (RNE), elem0 in low half
__device__ __forceinline__ u32 cvtpk(float lo, float hi) {
  u32 r;
  asm("v_cvt_pk_bf16_f32 %0, %1, %2" : "=v"(r) : "v"(lo), "v"(hi));
  return r;
}

// v_permlane32_swap_b32 a, b: a[32:63] <-> b[0:31]
__device__ __forceinline__ void plswap(u32& a, u32& b) {
  asm volatile("v_permlane32_swap_b32 %0, %1" : "+v"(a), "+v"(b));
}

__device__ __forceinline__ void gload16(const void* g, void* l) {
  typedef __attribute__((address_space(1))) unsigned int gu32;
  typedef __attribute__((address_space(3))) unsigned int lu32;
  __builtin_amdgcn_global_load_lds((gu32*)g, (lu32*)l, 16, 0, 0);
}

// ---------------- fp32 -> bf16 conversion of x1, x2, W ----------------
// Convert-once matters beyond FLOPs: bf16 panels keep the qkv staging working
// set L2-resident (R4 evidence: f32 direct reads -> FETCH 69->191MB, 1.75x slower).
// ~13us at ~5.6 TB/s aggregate: at the BW ceiling for its 73MB of traffic.
__global__ void convert_kernel(const fl4* __restrict__ x1, const fl4* __restrict__ x2,
                               const fl4* __restrict__ w,
                               us4* __restrict__ o1, us4* __restrict__ o2,
                               us4* __restrict__ ow) {
  const int NX = (B_ * N_ * D_) / 4;   // 1048576
  const int NW = (3 * D_ * D_) / 4;    // 786432
  int stride = gridDim.x * blockDim.x;
  for (int i = blockIdx.x * blockDim.x + threadIdx.x; i < NX; i += stride) {
    fl4 a = x1[i];
    us4 r; r.x = f2bf(a.x); r.y = f2bf(a.y); r.z = f2bf(a.z); r.w = f2bf(a.w);
    o1[i] = r;
    fl4 b = x2[i];
    us4 s; s.x = f2bf(b.x); s.y = f2bf(b.y); s.z = f2bf(b.z); s.w = f2bf(b.w);
    o2[i] = s;
    if (i < NW) {
      fl4 c = w[i];
      us4 t; t.x = f2bf(c.x); t.y = f2bf(c.y); t.z = f2bf(c.z); t.w = f2bf(c.w);
      ow[i] = t;
    }
  }
}

// ---------------- fused QKV GEMM v6 (CHAMPION, R8/R11: ~46-47us) ----------------
// 2-barrier K-loop, BK=64, global_load_lds, XOR-swizzled LDS (0 conflicts).
// Ledger (structural variants all regressed): 48.9 (2-bar BK32) / 49.7 (1-bar dbuf) /
// 61.9 (vmcnt ring) / 56.9 (z-XCD) / 47.0 (THIS) / 64.8 (256² 1-drain) / 101.9 (128x64).
// Swizzle: LINEAR gload_lds dest + inverse-swizzled global SOURCE (granule (l&7)^(l>>3),
// same 128B segment -> coalescing kept) + swizzled READ offsets ((quad^(col&7))*8, ^32).
// z=0: Q from x1 -> [B,H,N,HD] (pre-scaled by SCALE*log2e); z=1: K from x2; z=2: V -> Vt.
__global__ __launch_bounds__(256) void qkv_gemm(
    const u16* __restrict__ x1b, const u16* __restrict__ x2b,
    const u16* __restrict__ wb, const float* __restrict__ bias,
    u16* __restrict__ Qb, u16* __restrict__ Kb, u16* __restrict__ Vtb) {
  const int z = blockIdx.z;
  const u16* X = (z == 0) ? x1b : x2b;
  const u16* W = wb + (size_t)z * D_ * D_;
  const float* bz = bias + z * D_;
  const int m0 = blockIdx.y * 128;
  const int e0 = blockIdx.x * 128;
  const int tid = threadIdx.x;
  const int lane = tid & 63;
  const int w = tid >> 6;
  const int wr = w >> 1, wc = w & 1;
  const int col = lane & 15, quad = lane >> 4;

  __shared__ __align__(16) u16 As[128 * 64];   // [row][64], granule-swizzled
  __shared__ __align__(16) u16 Bs[128 * 64];

  f32x4 acc[4][4] = {};

  const int cg = (lane & 7) ^ (lane >> 3);
  const u16* sA = X + (size_t)(m0 + w * 8 + (lane >> 3)) * D_ + cg * 8;
  const u16* sB = W + (size_t)(e0 + w * 8 + (lane >> 3)) * D_ + cg * 8;
  u16* dA = &As[w * 512];                      // wave-uniform; HW adds lane*16B
  u16* dB = &Bs[w * 512];

  const int pg = (quad ^ (col & 7)) * 8;       // frag k=0..31; frag k=32..63 at pg^32

  for (int k0 = 0; k0 < D_; k0 += 64) {
    __syncthreads();                           // write-after-read: all waves done with tile
#pragma unroll
    for (int rr = 0; rr < 4; ++rr) {
      gload16(sA + (size_t)rr * 32 * D_ + k0, dA + rr * 2048);
      gload16(sB + (size_t)rr * 32 * D_ + k0, dB + rr * 2048);
    }
    __syncthreads();                           // drain: tile resident

    short8 a[4][2], b[4][2];
#pragma unroll
    for (int i = 0; i < 4; ++i) {
      const int rb = (wr * 64 + i * 16 + col) * 64;
      a[i][0] = *(const short8*)&As[rb + pg];
      a[i][1] = *(const short8*)&As[rb + (pg ^ 32)];
    }
#pragma unroll
    for (int j = 0; j < 4; ++j) {
      const int rb = (wc * 64 + j * 16 + col) * 64;
      b[j][0] = *(const short8*)&Bs[rb + pg];
      b[j][1] = *(const short8*)&Bs[rb + (pg ^ 32)];
    }
    __builtin_amdgcn_s_setprio(1);
#pragma unroll
    for (int i = 0; i < 4; ++i)
#pragma unroll
      for (int j = 0; j < 4; ++j) {
        acc[i][j] = __builtin_amdgcn_mfma_f32_16x16x32_bf16(a[i][0], b[j][0], acc[i][j], 0, 0, 0);
        acc[i][j] = __builtin_amdgcn_mfma_f32_16x16x32_bf16(a[i][1], b[j][1], acc[i][j], 0, 0, 0);
      }
    __builtin_amdgcn_s_setprio(0);
  }

#pragma unroll
  for (int j = 0; j < 4; ++j) {
    int eg = e0 + wc * 64 + j * 16 + col;
    float bj = bz[eg];
    int h = eg >> 6, d = eg & 63;
#pragma unroll
    for (int i = 0; i < 4; ++i) {
#pragma unroll
      for (int r = 0; r < 4; ++r) {
        int m = m0 + wr * 64 + i * 16 + quad * 4 + r;
        int bb = m >> 11, n = m & (N_ - 1);
        float v = acc[i][j][r] + bj;
        if (z == 0) v *= QSCALE_;
        u16 o = f2bf(v);
        if (z == 0)      Qb [(((size_t)bb * H_ + h) * N_ + n) * HD_ + d] = o;
        else if (z == 1) Kb [(((size_t)bb * H_ + h) * N_ + n) * HD_ + d] = o;
        else             Vtb[(((size_t)bb * H_ + h) * HD_ + d) * N_ + n] = o;
      }
    }
  }
}

// ---------------- fused attention v5 (CHAMPION, ~45.8us) ----------------
// 32x32 MFMA, swapped QK^T (S^T = mfma(K,Q): one q per lane), in-register softmax via
// cvt_pk_bf16 + permlane32_swap (T12) — no P LDS round-trip.  Denominator = per-lane
// scalar + 1 shfl.  K/V: double-buffered XOR-swizzled [64][64], 1 barrier/tile, 1-deep
// reg-staged prefetch.  R12 falsified 2-deep prefetch (null, +36 VGPR): the residual
// stall is the intra-tile serial chain (ds_read->QK->exp2->cvtpk->PV), not load latency.
__global__ __launch_bounds__(256, 2) void attn_kernel(
    const u16* __restrict__ Qb, const u16* __restrict__ Kb,
    const u16* __restrict__ Vtb, float* __restrict__ out) {
  const int bh = blockIdx.y;                 // 0..31
  const int bb = bh >> 4, h = bh & 15;
  const int q0 = blockIdx.x * 128;
  const int tid = threadIdx.x;
  const int lane = tid & 63;
  const int w = tid >> 6;
  const int l31 = lane & 31, hf = lane >> 5, r7 = lane & 7;

  const u16* __restrict__ Q  = Qb  + ((size_t)bh << 17);   // bh * N*HD
  const u16* __restrict__ K  = Kb  + ((size_t)bh << 17);
  const u16* __restrict__ Vt = Vtb + ((size_t)bh << 17);

  __shared__ __align__(16) u16 Ks[2][64 * 64];   // [buf][key][d]  swizzled
  __shared__ __align__(16) u16 Vs[2][64 * 64];   // [buf][d][key]  swizzled
  __shared__ float Ls[4][32];                    // per-wave 1/denominator

  // Q B-frags: col = q = l31, chunk c covers d = c*16 + hf*8 + j
  const u16* Qr = Q + (size_t)(q0 + w * 32 + l31) * HD_;
  short8 qf[4];
#pragma unroll
  for (int c = 0; c < 4; ++c)
    qf[c] = *(const short8*)&Qr[c * 16 + hf * 8];

  // cooperative staging: 256 threads x 16B granules; swizzled write slots
  const int srow = tid >> 3;              // 0..31
  const int sg   = tid & 7;
  const int lw0 = srow * 64 + ((sg ^ (srow & 7)) * 8);
  const int lw1 = lw0 + 2048;                            // row+32: (row&7) unchanged
  const u16* gK = K + tid * 8;                           // + k0*64 (+2048 rows 32..63)
  const u16* gV = Vt + srow * N_ + sg * 8;               // + k0   (+32*N_ d 32..63)

  f32x16 accO[2] = {};
  float lsum = 0.f;

  // prologue: tile 0 -> regs -> buf 0
  short8 kA = *(const short8*)(gK);
  short8 kB = *(const short8*)(gK + 2048);
  short8 vA = *(const short8*)(gV);
  short8 vB = *(const short8*)(gV + 32 * N_);
  *(short8*)&Ks[0][lw0] = kA;
  *(short8*)&Ks[0][lw1] = kB;
  *(short8*)&Vs[0][lw0] = vA;
  *(short8*)&Vs[0][lw1] = vB;

  for (int t = 0; t < N_ / 64; ++t) {
    __syncthreads();                     // buf[cur] writes visible to all waves
    const int cur = t & 1;
    if (t < N_ / 64 - 1) {               // prefetch next tile; consumed only by tail write
      const int k0n = (t + 1) * 64;
      kA = *(const short8*)(gK + k0n * 64);
      kB = *(const short8*)(gK + k0n * 64 + 2048);
      vA = *(const short8*)(gV + k0n);
      vB = *(const short8*)(gV + k0n + 32 * N_);
    }
    const u16* Kc = Ks[cur];
    const u16* Vc = Vs[cur];

    // S^T = K Q^T: A = K[key][d] (row=key=l31 per 32-block), B = Q (col=q)
    f32x16 sT[2] = {};
    __builtin_amdgcn_s_setprio(1);
#pragma unroll
    for (int kb = 0; kb < 2; ++kb) {
      const int rb = (kb * 32 + l31) * 64;
#pragma unroll
      for (int c = 0; c < 4; ++c) {
        short8 kf = *(const short8*)&Kc[rb + (((c * 2 + hf) ^ r7) * 8)];
        sT[kb] = __builtin_amdgcn_mfma_f32_32x32x16_bf16(kf, qf[c], sT[kb], 0, 0, 0);
      }
    }
    __builtin_amdgcn_s_setprio(0);

    // exp2 in-register (arg pre-scaled by SCALE*log2e; no max needed), scalar denom
#pragma unroll
    for (int kb = 0; kb < 2; ++kb)
#pragma unroll
      for (int i = 0; i < 16; ++i) {
        float e = EXP2F(sT[kb][i]);
        lsum += e;
        sT[kb][i] = e;
      }

    // build PV A-frags fully in-register: chunk kc = keys kc*16..+15 of the tile.
    short8 pf[4];
#pragma unroll
    for (int kc = 0; kc < 4; ++kc) {
      const int kb = kc >> 1, o = (kc & 1) * 8;
      u32 X = cvtpk(sT[kb][o + 0], sT[kb][o + 1]);
      u32 Y = cvtpk(sT[kb][o + 4], sT[kb][o + 5]);
      plswap(X, Y);
      u32 Z = cvtpk(sT[kb][o + 2], sT[kb][o + 3]);
      u32 W = cvtpk(sT[kb][o + 6], sT[kb][o + 7]);
      plswap(Z, W);
      u32x4 pw = {X, Z, Y, W};
      pf[kc] = __builtin_bit_cast(short8, pw);
    }

    // O += P V : A = P (row=q), B = V^T[d][key] (col=d), k=key
    __builtin_amdgcn_s_setprio(1);
#pragma unroll
    for (int db = 0; db < 2; ++db) {
      const int rb = (db * 32 + l31) * 64;
#pragma unroll
      for (int kc = 0; kc < 4; ++kc) {
        short8 vf = *(const short8*)&Vc[rb + (((kc * 2 + hf) ^ r7) * 8)];
        accO[db] = __builtin_amdgcn_mfma_f32_32x32x16_bf16(pf[kc], vf, accO[db], 0, 0, 0);
      }
    }
    __builtin_amdgcn_s_setprio(0);

    // tail: commit prefetched tile into the other buffer (vmcnt lands here, hidden)
    if (t < N_ / 64 - 1) {
      u16* Kn = (u16*)Ks[cur ^ 1];
      u16* Vn = (u16*)Vs[cur ^ 1];
      *(short8*)&Kn[lw0] = kA;
      *(short8*)&Kn[lw1] = kB;
      *(short8*)&Vn[lw0] = vA;
      *(short8*)&Vn[lw1] = vB;
    }
  }

  // denominator: lane pair (l, l^32) holds complementary key halves for q = l31
  lsum += __shfl_xor(lsum, 32);
  if (hf == 0) Ls[w][l31] = 1.0f / lsum;
  __syncthreads();

  float rinv[16];
#pragma unroll
  for (int r = 0; r < 16; ++r)
    rinv[r] = Ls[w][(r & 3) + 8 * (r >> 2) + 4 * hf];

#pragma unroll
  for (int db = 0; db < 2; ++db)
#pragma unroll
    for (int r = 0; r < 16; ++r) {
      int n = q0 + w * 32 + (r & 3) + 8 * (r >> 2) + 4 * hf;
      int e = h * HD_ + db * 32 + l31;
      out[((size_t)bb * N_ + n) * D_ + e] = accO[db][r] * rinv[r];
    }
}

extern "C" void kernel_launch(void* const* d_in, const int* in_sizes, int n_in,
                              void* d_out, int out_size, void* d_ws, size_t ws_size,
                              hipStream_t stream) {
  const float* x1 = (const float*)d_in[0];
  const float* x2 = (const float*)d_in[1];
  const float* qw = (const float*)d_in[2];
  const float* qb = (const float*)d_in[3];
  float* out = (float*)d_out;

  u16* ws   = (u16*)d_ws;
  u16* x1b  = ws;                       // 4194304
  u16* x2b  = ws + 4194304;             // 4194304
  u16* wb   = ws + 8388608;             // 3145728
  u16* Qbf  = ws + 11534336;            // 4194304  [B,H,N,HD] (pre-scaled)
  u16* Kbf  = ws + 15728640;            // 4194304  [B,H,N,HD]
  u16* Vtb  = ws + 19922944;            // 4194304  [B,H,HD,N]
  if (ws_size < (size_t)24117248 * 2) return;

  convert_kernel<<<dim3(1024), dim3(256), 0, stream>>>(
      (const fl4*)x1, (const fl4*)x2, (const fl4*)qw,
      (us4*)x1b, (us4*)x2b, (us4*)wb);

  qkv_gemm<<<dim3(8, 32, 3), dim3(256), 0, stream>>>(
      x1b, x2b, wb, qb, Qbf, Kbf, Vtb);

  attn_kernel<<<dim3(16, 32), dim3(256), 0, stream>>>(Qbf, Kbf, Vtb, out);
}